// Round 7
// baseline (570.704 us; speedup 1.0000x reference)
//
#include <hip/hip_runtime.h>
#include <cstdint>

// ---------------------------------------------------------------------------
// DDPM + VAE query encoder, MI355X round 19.
// r18 post-mortem: 419 MB static __device__ slab -> module/launch failure,
// out stayed memset-zero (absmax 2.0). Precompute theory still untested.
// r19 delivery mechanism #3: ws-adaptive CHUNKED precompute.
//  - noise slab = d_ws after the 2.2 MB of cproj/tpb/sched; S steps fit.
//  - host loop: k_noise(tstart,cnt) ; k_ddpm_chunk(tstart,cnt), x-state
//    handed off bit-exactly through `out` (fp32; free after k_enc).
//  - ws too small (S<13) -> r16-proven mono kernel (in-kernel noise).
// All paths draw identical threefry bits -> absmax unchanged.
// ---------------------------------------------------------------------------

#define DEVI __device__ __forceinline__

typedef __attribute__((ext_vector_type(8))) short short8;
typedef __attribute__((ext_vector_type(4))) float f32x4;

DEVI void threefry2x32(uint32_t k0, uint32_t k1, uint32_t x0, uint32_t x1,
                       uint32_t &o0, uint32_t &o1)
{
  const uint32_t ks2 = k0 ^ k1 ^ 0x1BD11BDAu;
  x0 += k0; x1 += k1;
#define TFR(r) { x0 += x1; x1 = __builtin_rotateleft32(x1, r); x1 ^= x0; }
  TFR(13u) TFR(15u) TFR(26u) TFR(6u)   x0 += k1;  x1 += ks2 + 1u;
  TFR(17u) TFR(29u) TFR(16u) TFR(24u)  x0 += ks2; x1 += k0 + 2u;
  TFR(13u) TFR(15u) TFR(26u) TFR(6u)   x0 += k0;  x1 += k1 + 3u;
  TFR(17u) TFR(29u) TFR(16u) TFR(24u)  x0 += k1;  x1 += ks2 + 4u;
  TFR(13u) TFR(15u) TFR(26u) TFR(6u)   x0 += ks2; x1 += k0 + 5u;
#undef TFR
  o0 = x0; o1 = x1;
}

DEVI uint32_t jax_random_bits32(uint32_t k0, uint32_t k1, uint32_t j)
{
  uint32_t a, b;
  threefry2x32(k0, k1, 0u, j, a, b);
  return a ^ b;
}

DEVI float jax_bits_to_normal(uint32_t bits)
{
  const float LO = -0.99999994f;
  float f = __uint_as_float((bits >> 9) | 0x3f800000u) - 1.0f;
  float u = fmaxf(LO, f * 2.0f + LO);
  float w = -__logf((1.0f - u) * (1.0f + u));
  float p;
  if (w < 5.0f) {
    w = w - 2.5f;
    p =              2.81022636e-08f;
    p = fmaf(p, w,   3.43273939e-07f);
    p = fmaf(p, w,  -3.5233877e-06f);
    p = fmaf(p, w,  -4.39150654e-06f);
    p = fmaf(p, w,   0.00021858087f);
    p = fmaf(p, w,  -0.00125372503f);
    p = fmaf(p, w,  -0.00417768164f);
    p = fmaf(p, w,   0.246640727f);
    p = fmaf(p, w,   1.50140941f);
  } else {
    w = sqrtf(w) - 3.0f;
    p =             -0.000200214257f;
    p = fmaf(p, w,   0.000100950558f);
    p = fmaf(p, w,   0.00134934322f);
    p = fmaf(p, w,  -0.00367342844f);
    p = fmaf(p, w,   0.00573950773f);
    p = fmaf(p, w,  -0.0076224613f);
    p = fmaf(p, w,   0.00943887047f);
    p = fmaf(p, w,   1.00167406f);
    p = fmaf(p, w,   2.83297682f);
  }
  return 1.41421356237f * (p * u);
}

DEVI short bf16_hi_trunc(float x) { return (short)(__float_as_uint(x) >> 16); }
DEVI float bf16_to_f32(short h)
{
  return __uint_as_float(((uint32_t)(unsigned short)h) << 16);
}
DEVI void split_bf16(float x, short &h, short &l)
{
  h = bf16_hi_trunc(x);
  float r = x - bf16_to_f32(h);
  l = bf16_hi_trunc(r);
}

// 8-short fragment from 16B-aligned LDS (stride-72 rows): one b128 read.
DEVI short8 ld_frag16(const short* p)
{
  union { int4 v; short8 s; } u;
  u.v = *(const int4*)p;
  return u.s;
}

// ---------------------------------------------------------------------------
__global__ __launch_bounds__(256)
void k_pool(const int* __restrict__ seq, const float* __restrict__ emb,
            float* __restrict__ pooled)
{
  const int lane = threadIdx.x & 63;
  const int r    = blockIdx.x * 4 + (threadIdx.x >> 6);
  const int* row = seq + r * 100;
  float s = 0.f;
  int cnt = 0;
  for (int l = 0; l < 100; ++l) {
    int id = row[l];
    cnt += (id != 0);
    s += emb[id * 64 + lane];
  }
  pooled[r * 64 + lane] = s / sqrtf((float)cnt);
}

// ---------------------------------------------------------------------------
__global__ __launch_bounds__(256)
void k_enc(const float* __restrict__ pooled,
           const float* __restrict__ W1, const float* __restrict__ b1,
           const float* __restrict__ W2, const float* __restrict__ b2,
           const float* __restrict__ Wc, const float* __restrict__ bc,
           float* __restrict__ cproj)
{
  __shared__ float p_s[8][64];
  __shared__ float h_s[8][256];
  __shared__ float mu_s[8][64];
  const int tid = threadIdx.x;
  const int r0  = blockIdx.x * 8;

  for (int i = tid; i < 8 * 64; i += 256)
    p_s[i >> 6][i & 63] = pooled[r0 * 64 + i];
  __syncthreads();

  float hacc[8];
#pragma unroll
  for (int r = 0; r < 8; ++r) hacc[r] = b1[tid];
  for (int k = 0; k < 64; ++k) {
    float w = W1[k * 256 + tid];
#pragma unroll
    for (int r = 0; r < 8; ++r) hacc[r] = fmaf(p_s[r][k], w, hacc[r]);
  }
#pragma unroll
  for (int r = 0; r < 8; ++r) h_s[r][tid] = fmaxf(hacc[r], 0.f);
  __syncthreads();

#pragma unroll
  for (int pass = 0; pass < 2; ++pass) {
    int r = pass * 4 + (tid >> 6);
    int j = tid & 63;
    float acc = b2[j];
    for (int k = 0; k < 256; ++k)
      acc = fmaf(h_s[r][k], W2[k * 128 + j], acc);
    mu_s[r][j] = acc;
  }
  __syncthreads();

#pragma unroll
  for (int pass = 0; pass < 2; ++pass) {
    int r = pass * 4 + (tid >> 6);
    int j = tid & 63;
    float acc = bc[j];
    for (int k = 0; k < 64; ++k)
      acc = fmaf(mu_s[r][k], Wc[k * 64 + j], acc);
    cproj[(r0 + r) * 64 + j] = acc;
  }
}

// ---------------------------------------------------------------------------
// k_prep: 200 blocks x 64 threads. Block t computes sched[t*8+..] AND
// tpb[t][d] = temb(t)@W_t + b_t + b_in.
__global__ __launch_bounds__(64)
void k_prep(const float* __restrict__ Wt, const float* __restrict__ bt,
            const float* __restrict__ bin, float* __restrict__ tpb,
            float* __restrict__ sched)
{
  __shared__ float temb[64];
  const int t = blockIdx.x;
  const int d = threadIdx.x;
  const float lg = logf(10000.0f);
  {
    int i = d & 31;
    float fr  = expf((-lg * (float)i) / 32.0f);
    float ang = (float)t * fr;
    temb[d] = (d < 32) ? cosf(ang) : sinf(ang);
  }
  if (d == 0) {
    const float start = (float)(5.0 * 1e-4);
    const float stop  = (float)(5.0 * 0.02);
    const float delta = stop - start;
    float prod = 1.f, acp_prev = 1.f, beta = 0.f, alpha = 1.f;
    for (int i = 0; i <= t; ++i) {
      beta  = start + ((float)i * delta) / 199.0f;
      alpha = 1.0f - beta;
      acp_prev = prod;
      prod = prod * alpha;
    }
    float acp = prod;
    float om  = 1.0f - acp;
    sched[t * 8 + 0] = sqrtf(1.0f / acp);
    sched[t * 8 + 1] = sqrtf(1.0f / acp - 1.0f);
    sched[t * 8 + 2] = beta * sqrtf(acp_prev) / om;
    sched[t * 8 + 3] = (1.0f - acp_prev) * sqrtf(alpha) / om;
    float pv = beta * (1.0f - acp_prev) / om;
    sched[t * 8 + 4] = (t > 0) ? sqrtf(pv) : 0.0f;
    uint32_t fk0, fk1;
    threefry2x32(0u, 2u, 0u, (uint32_t)t, fk0, fk1);
    ((uint32_t*)sched)[t * 8 + 5] = fk0;
    ((uint32_t*)sched)[t * 8 + 6] = fk1;
  }
  __syncthreads();
  float acc = bt[d] + bin[d];
  for (int k = 0; k < 64; ++k)
    acc = fmaf(temb[k], Wt[k * 64 + d], acc);
  tpb[t * 64 + d] = acc;
}

// ---------------------------------------------------------------------------
// k_noise: noise for steps tstart, tstart-1, ..., tstart-count+1 into the
// ws slab. slot = tstart - t. 4 values/thread, float4 store.
// grid = count*512 blocks x 256 threads (exactly count*524288 values).
__global__ __launch_bounds__(256)
void k_noise(const float* __restrict__ sched, float* __restrict__ noise,
             int tstart, int count)
{
  const uint32_t base = (blockIdx.x * 256u + threadIdx.x) * 4u;
  const uint32_t slot = base >> 19;          // 524288 values per step
  const uint32_t t = (uint32_t)tstart - slot;
  const uint32_t j = base & 524287u;
  const uint32_t fk0 = ((const uint32_t*)sched)[t * 8 + 5];
  const uint32_t fk1 = ((const uint32_t*)sched)[t * 8 + 6];
  float4 v;
  v.x = jax_bits_to_normal(jax_random_bits32(fk0, fk1, j + 0u));
  v.y = jax_bits_to_normal(jax_random_bits32(fk0, fk1, j + 1u));
  v.z = jax_bits_to_normal(jax_random_bits32(fk0, fk1, j + 2u));
  v.w = jax_bits_to_normal(jax_random_bits32(fk0, fk1, j + 3u));
  *(float4*)(noise + base) = v;
}

// ---------------------------------------------------------------------------
// K_ddpm_chunk: steps t = tstart .. tstart-count+1. x-state handed through
// `out` (fp32, bit-exact). tstart==199 -> draw x_init in-kernel.
// Same wave decomposition as r16: 512 blocks x 512 threads, full-K GEMV,
// weights in registers, LDS only X/H.
#define XLDW  72   // X/H row stride (shorts); 144 B -> 16B-aligned frags

__global__
__attribute__((amdgpu_flat_work_group_size(512, 512), amdgpu_waves_per_eu(4, 4)))
void k_ddpm_chunk(const float* __restrict__ Win, const float* __restrict__ Wout,
                  const float* __restrict__ bout,
                  const float* __restrict__ cproj, const float* __restrict__ tpb,
                  const float* __restrict__ sched, const float* __restrict__ noise,
                  float* __restrict__ out, int tstart, int count)
{
  __shared__ __align__(16) short Xh[16 * XLDW], Xl[16 * XLDW];
  __shared__ __align__(16) short Hh[16 * XLDW], Hl[16 * XLDW];

  const int tid  = threadIdx.x;
  const int lane = tid & 63;
  const int w    = tid >> 6;
  const int nt   = w & 3;
  const int kc   = w >> 2;
  const int nn   = lane & 15;
  const int quad = lane >> 4;
  const int dim  = nt * 16 + nn;
  const int arow = nn;
  const int r0g  = blockIdx.x * 16;
  const int kq0  = quad * 8;
  const int kq1  = 32 + quad * 8;
  const int rA   = quad * 4 + 2 * kc;

  short8 wiH0, wiL0, wiH1, wiL1, woH0, woL0, woH1, woL1;
#pragma unroll
  for (int j = 0; j < 8; ++j) {
    short h, l;
    split_bf16(Win[(kq0 + j) * 64 + dim], h, l);  wiH0[j] = h; wiL0[j] = l;
    split_bf16(Win[(kq1 + j) * 64 + dim], h, l);  wiH1[j] = h; wiL1[j] = l;
    split_bf16(Wout[(kq0 + j) * 64 + dim], h, l); woH0[j] = h; woL0[j] = l;
    split_bf16(Wout[(kq1 + j) * 64 + dim], h, l); woH1[j] = h; woL1[j] = l;
  }

  const float bo = bout[dim];
  const uint32_t jA = (uint32_t)((r0g + rA) * 64 + dim);
  const uint32_t jB = jA + 64u;
  const float cpA = cproj[jA];
  const float cpB = cproj[jB];

  float xoA, xoB;
  if (tstart == 199) {
    xoA = jax_bits_to_normal(jax_random_bits32(0u, 1u, jA));
    xoB = jax_bits_to_normal(jax_random_bits32(0u, 1u, jB));
  } else {
    xoA = out[jA];
    xoB = out[jB];
  }
  {
    short h, l;
    split_bf16(xoA, h, l); Xh[rA * XLDW + dim] = h; Xl[rA * XLDW + dim] = l;
    split_bf16(xoB, h, l); Xh[(rA+1) * XLDW + dim] = h; Xl[(rA+1) * XLDW + dim] = l;
  }
  __syncthreads();

  float tp = tpb[tstart * 64 + dim];
  const int tend = tstart - count + 1;

#pragma unroll 1
  for (int t = tstart; t >= tend; --t) {
    const float sr   = sched[t * 8 + 0];
    const float srm1 = sched[t * 8 + 1];
    const float c1   = sched[t * 8 + 2];
    const float c2   = sched[t * 8 + 3];
    const float sg   = sched[t * 8 + 4];

    // noise loads issued at step start, consumed at step end
    const float* np = noise + (uint32_t)(tstart - t) * 524288u;
    float nA = np[jA];
    float nB = np[jB];

    // ---- phase A: in-GEMV, FULL K=64
    f32x4 acc;
    if (kc == 0) { acc[0] = tp + cpA; acc[1] = tp + cpB; acc[2] = 0.f; acc[3] = 0.f; }
    else         { acc[0] = 0.f; acc[1] = 0.f; acc[2] = tp + cpA; acc[3] = tp + cpB; }
    {
      short8 xh0 = ld_frag16(&Xh[arow * XLDW + kq0]);
      short8 xl0 = ld_frag16(&Xl[arow * XLDW + kq0]);
      short8 xh1 = ld_frag16(&Xh[arow * XLDW + kq1]);
      short8 xl1 = ld_frag16(&Xl[arow * XLDW + kq1]);
      acc = __builtin_amdgcn_mfma_f32_16x16x32_bf16(xl0, wiH0, acc, 0, 0, 0);
      acc = __builtin_amdgcn_mfma_f32_16x16x32_bf16(xh0, wiL0, acc, 0, 0, 0);
      acc = __builtin_amdgcn_mfma_f32_16x16x32_bf16(xh0, wiH0, acc, 0, 0, 0);
      acc = __builtin_amdgcn_mfma_f32_16x16x32_bf16(xl1, wiH1, acc, 0, 0, 0);
      acc = __builtin_amdgcn_mfma_f32_16x16x32_bf16(xh1, wiL1, acc, 0, 0, 0);
      acc = __builtin_amdgcn_mfma_f32_16x16x32_bf16(xh1, wiH1, acc, 0, 0, 0);
    }
    {
      float vA, vB;
      if (kc == 0) { vA = acc[0]; vB = acc[1]; }
      else         { vA = acc[2]; vB = acc[3]; }
      vA = vA * __builtin_amdgcn_rcpf(1.0f + __expf(-vA));
      vB = vB * __builtin_amdgcn_rcpf(1.0f + __expf(-vB));
      short h, l;
      split_bf16(vA, h, l); Hh[rA * XLDW + dim] = h; Hl[rA * XLDW + dim] = l;
      split_bf16(vB, h, l); Hh[(rA+1) * XLDW + dim] = h; Hl[(rA+1) * XLDW + dim] = l;
    }
    int tn = (t > 0) ? (t - 1) : 0;
    float tpn = tpb[tn * 64 + dim];
    __syncthreads();                                    // B1

    // ---- phase B: out-GEMV, FULL K=64, update + restage X
    f32x4 eac;
    if (kc == 0) { eac[0] = bo; eac[1] = bo; eac[2] = 0.f; eac[3] = 0.f; }
    else         { eac[0] = 0.f; eac[1] = 0.f; eac[2] = bo; eac[3] = bo; }
    {
      short8 hh0 = ld_frag16(&Hh[arow * XLDW + kq0]);
      short8 hl0 = ld_frag16(&Hl[arow * XLDW + kq0]);
      short8 hh1 = ld_frag16(&Hh[arow * XLDW + kq1]);
      short8 hl1 = ld_frag16(&Hl[arow * XLDW + kq1]);
      eac = __builtin_amdgcn_mfma_f32_16x16x32_bf16(hl0, woH0, eac, 0, 0, 0);
      eac = __builtin_amdgcn_mfma_f32_16x16x32_bf16(hh0, woL0, eac, 0, 0, 0);
      eac = __builtin_amdgcn_mfma_f32_16x16x32_bf16(hh0, woH0, eac, 0, 0, 0);
      eac = __builtin_amdgcn_mfma_f32_16x16x32_bf16(hl1, woH1, eac, 0, 0, 0);
      eac = __builtin_amdgcn_mfma_f32_16x16x32_bf16(hh1, woL1, eac, 0, 0, 0);
      eac = __builtin_amdgcn_mfma_f32_16x16x32_bf16(hh1, woH1, eac, 0, 0, 0);
    }
    {
      float eA, eB;
      if (kc == 0) { eA = eac[0]; eB = eac[1]; }
      else         { eA = eac[2]; eB = eac[3]; }
      float xcA = fminf(1.f, fmaxf(-1.f, sr * xoA - srm1 * eA));
      float xcB = fminf(1.f, fmaxf(-1.f, sr * xoB - srm1 * eB));
      xoA = c1 * xcA + c2 * xoA + sg * nA;
      xoB = c1 * xcB + c2 * xoB + sg * nB;
      short h, l;
      split_bf16(xoA, h, l); Xh[rA * XLDW + dim] = h; Xl[rA * XLDW + dim] = l;
      split_bf16(xoB, h, l); Xh[(rA+1) * XLDW + dim] = h; Xl[(rA+1) * XLDW + dim] = l;
      tp = tpn;
    }
    __syncthreads();                                    // B2
  }

  // state handoff (and final result on the last chunk)
  out[jA] = xoA;
  out[jB] = xoB;
}

// ---------------------------------------------------------------------------
// K_ddpm_mono: r16-proven fallback (in-kernel noise), used when ws is too
// small for chunked precompute.
__global__
__attribute__((amdgpu_flat_work_group_size(512, 512), amdgpu_waves_per_eu(4, 4)))
void k_ddpm_mono(const float* __restrict__ Win, const float* __restrict__ Wout,
                 const float* __restrict__ bout,
                 const float* __restrict__ cproj, const float* __restrict__ tpb,
                 const float* __restrict__ sched, float* __restrict__ out)
{
  __shared__ __align__(16) short Xh[16 * XLDW], Xl[16 * XLDW];
  __shared__ __align__(16) short Hh[16 * XLDW], Hl[16 * XLDW];

  const int tid  = threadIdx.x;
  const int lane = tid & 63;
  const int w    = tid >> 6;
  const int nt   = w & 3;
  const int kc   = w >> 2;
  const int nn   = lane & 15;
  const int quad = lane >> 4;
  const int dim  = nt * 16 + nn;
  const int arow = nn;
  const int r0g  = blockIdx.x * 16;
  const int kq0  = quad * 8;
  const int kq1  = 32 + quad * 8;
  const int rA   = quad * 4 + 2 * kc;

  short8 wiH0, wiL0, wiH1, wiL1, woH0, woL0, woH1, woL1;
#pragma unroll
  for (int j = 0; j < 8; ++j) {
    short h, l;
    split_bf16(Win[(kq0 + j) * 64 + dim], h, l);  wiH0[j] = h; wiL0[j] = l;
    split_bf16(Win[(kq1 + j) * 64 + dim], h, l);  wiH1[j] = h; wiL1[j] = l;
    split_bf16(Wout[(kq0 + j) * 64 + dim], h, l); woH0[j] = h; woL0[j] = l;
    split_bf16(Wout[(kq1 + j) * 64 + dim], h, l); woH1[j] = h; woL1[j] = l;
  }

  const float bo = bout[dim];
  const uint32_t jA = (uint32_t)((r0g + rA) * 64 + dim);
  const uint32_t jB = jA + 64u;
  const float cpA = cproj[jA];
  const float cpB = cproj[jB];

  float xoA = jax_bits_to_normal(jax_random_bits32(0u, 1u, jA));
  float xoB = jax_bits_to_normal(jax_random_bits32(0u, 1u, jB));
  {
    short h, l;
    split_bf16(xoA, h, l); Xh[rA * XLDW + dim] = h; Xl[rA * XLDW + dim] = l;
    split_bf16(xoB, h, l); Xh[(rA+1) * XLDW + dim] = h; Xl[(rA+1) * XLDW + dim] = l;
  }
  __syncthreads();

  float tp = tpb[199 * 64 + dim];

#pragma unroll 1
  for (int t = 199; t >= 0; --t) {
    const float sr   = sched[t * 8 + 0];
    const float srm1 = sched[t * 8 + 1];
    const float c1   = sched[t * 8 + 2];
    const float c2   = sched[t * 8 + 3];
    const float sg   = sched[t * 8 + 4];
    const uint32_t fk0 = ((const uint32_t*)sched)[t * 8 + 5];
    const uint32_t fk1 = ((const uint32_t*)sched)[t * 8 + 6];

    float nA = jax_bits_to_normal(jax_random_bits32(fk0, fk1, jA));
    float nB = jax_bits_to_normal(jax_random_bits32(fk0, fk1, jB));

    f32x4 acc;
    if (kc == 0) { acc[0] = tp + cpA; acc[1] = tp + cpB; acc[2] = 0.f; acc[3] = 0.f; }
    else         { acc[0] = 0.f; acc[1] = 0.f; acc[2] = tp + cpA; acc[3] = tp + cpB; }
    {
      short8 xh0 = ld_frag16(&Xh[arow * XLDW + kq0]);
      short8 xl0 = ld_frag16(&Xl[arow * XLDW + kq0]);
      short8 xh1 = ld_frag16(&Xh[arow * XLDW + kq1]);
      short8 xl1 = ld_frag16(&Xl[arow * XLDW + kq1]);
      acc = __builtin_amdgcn_mfma_f32_16x16x32_bf16(xl0, wiH0, acc, 0, 0, 0);
      acc = __builtin_amdgcn_mfma_f32_16x16x32_bf16(xh0, wiL0, acc, 0, 0, 0);
      acc = __builtin_amdgcn_mfma_f32_16x16x32_bf16(xh0, wiH0, acc, 0, 0, 0);
      acc = __builtin_amdgcn_mfma_f32_16x16x32_bf16(xl1, wiH1, acc, 0, 0, 0);
      acc = __builtin_amdgcn_mfma_f32_16x16x32_bf16(xh1, wiL1, acc, 0, 0, 0);
      acc = __builtin_amdgcn_mfma_f32_16x16x32_bf16(xh1, wiH1, acc, 0, 0, 0);
    }
    {
      float vA, vB;
      if (kc == 0) { vA = acc[0]; vB = acc[1]; }
      else         { vA = acc[2]; vB = acc[3]; }
      vA = vA * __builtin_amdgcn_rcpf(1.0f + __expf(-vA));
      vB = vB * __builtin_amdgcn_rcpf(1.0f + __expf(-vB));
      short h, l;
      split_bf16(vA, h, l); Hh[rA * XLDW + dim] = h; Hl[rA * XLDW + dim] = l;
      split_bf16(vB, h, l); Hh[(rA+1) * XLDW + dim] = h; Hl[(rA+1) * XLDW + dim] = l;
    }
    int tn = (t > 0) ? (t - 1) : 0;
    float tpn = tpb[tn * 64 + dim];
    __syncthreads();                                    // B1

    f32x4 eac;
    if (kc == 0) { eac[0] = bo; eac[1] = bo; eac[2] = 0.f; eac[3] = 0.f; }
    else         { eac[0] = 0.f; eac[1] = 0.f; eac[2] = bo; eac[3] = bo; }
    {
      short8 hh0 = ld_frag16(&Hh[arow * XLDW + kq0]);
      short8 hl0 = ld_frag16(&Hl[arow * XLDW + kq0]);
      short8 hh1 = ld_frag16(&Hh[arow * XLDW + kq1]);
      short8 hl1 = ld_frag16(&Hl[arow * XLDW + kq1]);
      eac = __builtin_amdgcn_mfma_f32_16x16x32_bf16(hl0, woH0, eac, 0, 0, 0);
      eac = __builtin_amdgcn_mfma_f32_16x16x32_bf16(hh0, woL0, eac, 0, 0, 0);
      eac = __builtin_amdgcn_mfma_f32_16x16x32_bf16(hh0, woH0, eac, 0, 0, 0);
      eac = __builtin_amdgcn_mfma_f32_16x16x32_bf16(hl1, woH1, eac, 0, 0, 0);
      eac = __builtin_amdgcn_mfma_f32_16x16x32_bf16(hh1, woL1, eac, 0, 0, 0);
      eac = __builtin_amdgcn_mfma_f32_16x16x32_bf16(hh1, woH1, eac, 0, 0, 0);
    }
    {
      float eA, eB;
      if (kc == 0) { eA = eac[0]; eB = eac[1]; }
      else         { eA = eac[2]; eB = eac[3]; }
      float xcA = fminf(1.f, fmaxf(-1.f, sr * xoA - srm1 * eA));
      float xcB = fminf(1.f, fmaxf(-1.f, sr * xoB - srm1 * eB));
      xoA = c1 * xcA + c2 * xoA + sg * nA;
      xoB = c1 * xcB + c2 * xoB + sg * nB;
      short h, l;
      split_bf16(xoA, h, l); Xh[rA * XLDW + dim] = h; Xl[rA * XLDW + dim] = l;
      split_bf16(xoB, h, l); Xh[(rA+1) * XLDW + dim] = h; Xl[(rA+1) * XLDW + dim] = l;
      tp = tpn;
    }
    __syncthreads();                                    // B2
  }

  out[jA] = xoA;
  out[jB] = xoB;
}

// ---------------------------------------------------------------------------
extern "C" void kernel_launch(void* const* d_in, const int* in_sizes, int n_in,
                              void* d_out, int out_size, void* d_ws, size_t ws_size,
                              hipStream_t stream)
{
  const int*   seq  = (const int*)  d_in[0];
  const float* emb  = (const float*)d_in[1];
  const float* W1   = (const float*)d_in[2];
  const float* b1   = (const float*)d_in[3];
  const float* W2   = (const float*)d_in[4];
  const float* b2   = (const float*)d_in[5];
  const float* Win  = (const float*)d_in[6];
  const float* bin  = (const float*)d_in[7];
  const float* Wt   = (const float*)d_in[8];
  const float* bt   = (const float*)d_in[9];
  const float* Wc   = (const float*)d_in[10];
  const float* bc   = (const float*)d_in[11];
  const float* Wout = (const float*)d_in[12];
  const float* bout = (const float*)d_in[13];

  float* out   = (float*)d_out;
  float* ws    = (float*)d_ws;
  float* cproj = ws;                       // 524288 floats
  float* tpb   = ws + 524288;              // 12800 floats
  float* sched = ws + 524288 + 12800;      // 1600 floats (t*8 layout)
  float* noise = ws + 538688;              // chunk slab (rest of ws)
  float* pooled = out;                     // reuse d_out as scratch

  // steps of noise that fit in the remaining workspace
  long long navail = (long long)(ws_size / 4) - 538688ll;
  int S = (navail > 0) ? (int)(navail / 524288ll) : 0;
  if (S > 200) S = 200;

  k_pool <<<2048, 256, 0, stream>>>(seq, emb, pooled);
  k_enc  <<<1024, 256, 0, stream>>>(pooled, W1, b1, W2, b2, Wc, bc, cproj);
  k_prep <<<200, 64, 0, stream>>>(Wt, bt, bin, tpb, sched);

  if (S >= 13) {
    int t = 199;
    while (t >= 0) {
      int cnt = (t + 1 < S) ? (t + 1) : S;
      k_noise<<<cnt * 512, 256, 0, stream>>>(sched, noise, t, cnt);
      k_ddpm_chunk<<<512, 512, 0, stream>>>(Win, Wout, bout, cproj, tpb,
                                            sched, noise, out, t, cnt);
      t -= cnt;
    }
  } else {
    k_ddpm_mono<<<512, 512, 0, stream>>>(Win, Wout, bout, cproj, tpb, sched, out);
  }
}

// Round 8
// 543.536 us; speedup vs baseline: 1.0500x; 1.0500x over previous
//
#include <hip/hip_runtime.h>
#include <cstdint>

// ---------------------------------------------------------------------------
// DDPM + VAE query encoder, MI355X round 20.
// r19 post-mortem: precompute CONFIRMED the decomposition (noise ~259 us
// issue-bound; GEMV loop ~266 us latency-bound) but stream-serial split wins
// nothing (259+266 ~= mono 463). Fix: overlap INSIDE one kernel via wave
// specialization. 512 blocks x 512 thr (proven no-spill regime):
//  - waves 0-3 (GEMV): one 16-col group each, keep ALL 4 acc rows
//    (acc[reg] = row quad*4+reg) -> kc duplication gone, MFMA halves,
//    per-element arithmetic bit-identical to r16.
//  - waves 4-7 (noise): produce step t-1's 1024 values into double-buffered
//    LDS nbuf[2][16][68] (2 draws before B1, 2 after) while GEMV waves chew
//    step t. PRNG leaves the critical path; issue slots it used were idle.
// Same 2 barriers/step; same threefry bits via LDS -> absmax unchanged.
// ws noise slab + extra kernels deleted.
// ---------------------------------------------------------------------------

#define DEVI __device__ __forceinline__

typedef __attribute__((ext_vector_type(8))) short short8;
typedef __attribute__((ext_vector_type(4))) float f32x4;

DEVI void threefry2x32(uint32_t k0, uint32_t k1, uint32_t x0, uint32_t x1,
                       uint32_t &o0, uint32_t &o1)
{
  const uint32_t ks2 = k0 ^ k1 ^ 0x1BD11BDAu;
  x0 += k0; x1 += k1;
#define TFR(r) { x0 += x1; x1 = __builtin_rotateleft32(x1, r); x1 ^= x0; }
  TFR(13u) TFR(15u) TFR(26u) TFR(6u)   x0 += k1;  x1 += ks2 + 1u;
  TFR(17u) TFR(29u) TFR(16u) TFR(24u)  x0 += ks2; x1 += k0 + 2u;
  TFR(13u) TFR(15u) TFR(26u) TFR(6u)   x0 += k0;  x1 += k1 + 3u;
  TFR(17u) TFR(29u) TFR(16u) TFR(24u)  x0 += k1;  x1 += ks2 + 4u;
  TFR(13u) TFR(15u) TFR(26u) TFR(6u)   x0 += ks2; x1 += k0 + 5u;
#undef TFR
  o0 = x0; o1 = x1;
}

DEVI uint32_t jax_random_bits32(uint32_t k0, uint32_t k1, uint32_t j)
{
  uint32_t a, b;
  threefry2x32(k0, k1, 0u, j, a, b);
  return a ^ b;
}

DEVI float jax_bits_to_normal(uint32_t bits)
{
  const float LO = -0.99999994f;
  float f = __uint_as_float((bits >> 9) | 0x3f800000u) - 1.0f;
  float u = fmaxf(LO, f * 2.0f + LO);
  float w = -__logf((1.0f - u) * (1.0f + u));
  float p;
  if (w < 5.0f) {
    w = w - 2.5f;
    p =              2.81022636e-08f;
    p = fmaf(p, w,   3.43273939e-07f);
    p = fmaf(p, w,  -3.5233877e-06f);
    p = fmaf(p, w,  -4.39150654e-06f);
    p = fmaf(p, w,   0.00021858087f);
    p = fmaf(p, w,  -0.00125372503f);
    p = fmaf(p, w,  -0.00417768164f);
    p = fmaf(p, w,   0.246640727f);
    p = fmaf(p, w,   1.50140941f);
  } else {
    w = sqrtf(w) - 3.0f;
    p =             -0.000200214257f;
    p = fmaf(p, w,   0.000100950558f);
    p = fmaf(p, w,   0.00134934322f);
    p = fmaf(p, w,  -0.00367342844f);
    p = fmaf(p, w,   0.00573950773f);
    p = fmaf(p, w,  -0.0076224613f);
    p = fmaf(p, w,   0.00943887047f);
    p = fmaf(p, w,   1.00167406f);
    p = fmaf(p, w,   2.83297682f);
  }
  return 1.41421356237f * (p * u);
}

DEVI short bf16_hi_trunc(float x) { return (short)(__float_as_uint(x) >> 16); }
DEVI float bf16_to_f32(short h)
{
  return __uint_as_float(((uint32_t)(unsigned short)h) << 16);
}
DEVI void split_bf16(float x, short &h, short &l)
{
  h = bf16_hi_trunc(x);
  float r = x - bf16_to_f32(h);
  l = bf16_hi_trunc(r);
}

// 8-short fragment from 16B-aligned LDS (stride-72 rows): one b128 read.
DEVI short8 ld_frag16(const short* p)
{
  union { int4 v; short8 s; } u;
  u.v = *(const int4*)p;
  return u.s;
}

// ---------------------------------------------------------------------------
__global__ __launch_bounds__(256)
void k_pool(const int* __restrict__ seq, const float* __restrict__ emb,
            float* __restrict__ pooled)
{
  const int lane = threadIdx.x & 63;
  const int r    = blockIdx.x * 4 + (threadIdx.x >> 6);
  const int* row = seq + r * 100;
  float s = 0.f;
  int cnt = 0;
  for (int l = 0; l < 100; ++l) {
    int id = row[l];
    cnt += (id != 0);
    s += emb[id * 64 + lane];
  }
  pooled[r * 64 + lane] = s / sqrtf((float)cnt);
}

// ---------------------------------------------------------------------------
__global__ __launch_bounds__(256)
void k_enc(const float* __restrict__ pooled,
           const float* __restrict__ W1, const float* __restrict__ b1,
           const float* __restrict__ W2, const float* __restrict__ b2,
           const float* __restrict__ Wc, const float* __restrict__ bc,
           float* __restrict__ cproj)
{
  __shared__ float p_s[8][64];
  __shared__ float h_s[8][256];
  __shared__ float mu_s[8][64];
  const int tid = threadIdx.x;
  const int r0  = blockIdx.x * 8;

  for (int i = tid; i < 8 * 64; i += 256)
    p_s[i >> 6][i & 63] = pooled[r0 * 64 + i];
  __syncthreads();

  float hacc[8];
#pragma unroll
  for (int r = 0; r < 8; ++r) hacc[r] = b1[tid];
  for (int k = 0; k < 64; ++k) {
    float w = W1[k * 256 + tid];
#pragma unroll
    for (int r = 0; r < 8; ++r) hacc[r] = fmaf(p_s[r][k], w, hacc[r]);
  }
#pragma unroll
  for (int r = 0; r < 8; ++r) h_s[r][tid] = fmaxf(hacc[r], 0.f);
  __syncthreads();

#pragma unroll
  for (int pass = 0; pass < 2; ++pass) {
    int r = pass * 4 + (tid >> 6);
    int j = tid & 63;
    float acc = b2[j];
    for (int k = 0; k < 256; ++k)
      acc = fmaf(h_s[r][k], W2[k * 128 + j], acc);
    mu_s[r][j] = acc;
  }
  __syncthreads();

#pragma unroll
  for (int pass = 0; pass < 2; ++pass) {
    int r = pass * 4 + (tid >> 6);
    int j = tid & 63;
    float acc = bc[j];
    for (int k = 0; k < 64; ++k)
      acc = fmaf(mu_s[r][k], Wc[k * 64 + j], acc);
    cproj[(r0 + r) * 64 + j] = acc;
  }
}

// ---------------------------------------------------------------------------
// k_prep: 200 blocks x 64 threads. Block t computes sched[t*8+..] AND
// tpb[t][d] = temb(t)@W_t + b_t + b_in.
__global__ __launch_bounds__(64)
void k_prep(const float* __restrict__ Wt, const float* __restrict__ bt,
            const float* __restrict__ bin, float* __restrict__ tpb,
            float* __restrict__ sched)
{
  __shared__ float temb[64];
  const int t = blockIdx.x;
  const int d = threadIdx.x;
  const float lg = logf(10000.0f);
  {
    int i = d & 31;
    float fr  = expf((-lg * (float)i) / 32.0f);
    float ang = (float)t * fr;
    temb[d] = (d < 32) ? cosf(ang) : sinf(ang);
  }
  if (d == 0) {
    const float start = (float)(5.0 * 1e-4);
    const float stop  = (float)(5.0 * 0.02);
    const float delta = stop - start;
    float prod = 1.f, acp_prev = 1.f, beta = 0.f, alpha = 1.f;
    for (int i = 0; i <= t; ++i) {
      beta  = start + ((float)i * delta) / 199.0f;
      alpha = 1.0f - beta;
      acp_prev = prod;
      prod = prod * alpha;
    }
    float acp = prod;
    float om  = 1.0f - acp;
    sched[t * 8 + 0] = sqrtf(1.0f / acp);
    sched[t * 8 + 1] = sqrtf(1.0f / acp - 1.0f);
    sched[t * 8 + 2] = beta * sqrtf(acp_prev) / om;
    sched[t * 8 + 3] = (1.0f - acp_prev) * sqrtf(alpha) / om;
    float pv = beta * (1.0f - acp_prev) / om;
    sched[t * 8 + 4] = (t > 0) ? sqrtf(pv) : 0.0f;
    uint32_t fk0, fk1;
    threefry2x32(0u, 2u, 0u, (uint32_t)t, fk0, fk1);
    ((uint32_t*)sched)[t * 8 + 5] = fk0;
    ((uint32_t*)sched)[t * 8 + 6] = fk1;
  }
  __syncthreads();
  float acc = bt[d] + bin[d];
  for (int k = 0; k < 64; ++k)
    acc = fmaf(temb[k], Wt[k * 64 + d], acc);
  tpb[t * 64 + d] = acc;
}

// ---------------------------------------------------------------------------
// K_ddpm: 512 blocks x 512 threads (8 waves). Block owns 16 rows.
// Waves 0-3 (GEMV): wave nt owns cols 16nt..16nt+15; lane (quad,nn) owns
//   rows quad*4+0..3 (the 4 acc regs) at col dim. Full-K GEMV (6 MFMA/phase).
// Waves 4-7 (noise): produce step t-1's 16x64 noise into nbuf[(t-1)&1]
//   (2 draws before B1, 2 after) while GEMV waves compute step t.
#define XLDW  72   // X/H row stride (shorts); 144 B -> 16B-aligned frags
#define NBW   68   // nbuf row stride (floats): quad spread -> 2-way banks

__global__
__attribute__((amdgpu_flat_work_group_size(512, 512), amdgpu_waves_per_eu(4, 4)))
void k_ddpm(const float* __restrict__ Win, const float* __restrict__ Wout,
            const float* __restrict__ bout,
            const float* __restrict__ cproj, const float* __restrict__ tpb,
            const float* __restrict__ sched, float* __restrict__ out)
{
  __shared__ __align__(16) short Xh[16 * XLDW], Xl[16 * XLDW];
  __shared__ __align__(16) short Hh[16 * XLDW], Hl[16 * XLDW];
  __shared__ __align__(16) float nbuf[2 * 16 * NBW];
  // total: 4*2304 + 8704 = 17920 B

  const int tid  = threadIdx.x;
  const int lane = tid & 63;
  const int w    = tid >> 6;
  const bool gemv = (w < 4);
  const int r0g  = blockIdx.x * 16;
  const uint32_t* su = (const uint32_t*)sched;

  // ---- GEMV-wave ids
  const int nt   = w & 3;          // col group (gemv waves: w==nt)
  const int nn   = lane & 15;
  const int quad = lane >> 4;
  const int dim  = nt * 16 + nn;
  const int arow = nn;
  const int kq0  = quad * 8;
  const int kq1  = 32 + quad * 8;
  const int rowb = quad * 4;                       // owned rows rowb..rowb+3

  // ---- noise-wave ids: q in [0,256), 4 consecutive cells
  const int q    = (w - 4) * 64 + lane;
  const int cb   = q * 4;                          // cell base (row*64+dim)
  const uint32_t jn = (uint32_t)(r0g * 64 + cb);   // global noise index base
  const int nrow = cb >> 6;
  const int ndim = cb & 63;
  float* nb_w = &nbuf[nrow * NBW + ndim];          // + buf*16*NBW at use

  // ---- GEMV state
  short8 wiH0, wiL0, wiH1, wiL1, woH0, woL0, woH1, woL1;
  float cp[4], xo[4];
  float bo = 0.f, tp = 0.f;
  uint32_t j0 = 0;

  if (gemv) {
#pragma unroll
    for (int j = 0; j < 8; ++j) {
      short h, l;
      split_bf16(Win[(kq0 + j) * 64 + dim], h, l);  wiH0[j] = h; wiL0[j] = l;
      split_bf16(Win[(kq1 + j) * 64 + dim], h, l);  wiH1[j] = h; wiL1[j] = l;
      split_bf16(Wout[(kq0 + j) * 64 + dim], h, l); woH0[j] = h; woL0[j] = l;
      split_bf16(Wout[(kq1 + j) * 64 + dim], h, l); woH1[j] = h; woL1[j] = l;
    }
    bo = bout[dim];
    j0 = (uint32_t)((r0g + rowb) * 64 + dim);
#pragma unroll
    for (int r = 0; r < 4; ++r) cp[r] = cproj[j0 + r * 64u];
#pragma unroll
    for (int r = 0; r < 4; ++r) {
      xo[r] = jax_bits_to_normal(jax_random_bits32(0u, 1u, j0 + r * 64u));
      short h, l;
      split_bf16(xo[r], h, l);
      Xh[(rowb + r) * XLDW + dim] = h; Xl[(rowb + r) * XLDW + dim] = l;
    }
    tp = tpb[199 * 64 + dim];
  } else {
    // prologue: noise for t=199 into nbuf[1]
    const uint32_t fk0 = su[199 * 8 + 5];
    const uint32_t fk1 = su[199 * 8 + 6];
    float* d = nb_w + 16 * NBW;                    // buf 1
    d[0] = jax_bits_to_normal(jax_random_bits32(fk0, fk1, jn + 0u));
    d[1] = jax_bits_to_normal(jax_random_bits32(fk0, fk1, jn + 1u));
    d[2] = jax_bits_to_normal(jax_random_bits32(fk0, fk1, jn + 2u));
    d[3] = jax_bits_to_normal(jax_random_bits32(fk0, fk1, jn + 3u));
  }
  __syncthreads();

#pragma unroll 1
  for (int t = 199; t >= 0; --t) {
    float sr = 0.f, srm1 = 0.f, c1 = 0.f, c2 = 0.f, sg = 0.f;
    float n[4], tpn = 0.f;
    f32x4 acc;
    uint32_t gk0 = 0, gk1 = 0;
    float* nd = nullptr;

    if (gemv) {
      sr   = sched[t * 8 + 0];
      srm1 = sched[t * 8 + 1];
      c1   = sched[t * 8 + 2];
      c2   = sched[t * 8 + 3];
      sg   = sched[t * 8 + 4];
      // noise for this step (produced >= one barrier-pair ago)
      const float* nr = &nbuf[(t & 1) * 16 * NBW + rowb * NBW + dim];
#pragma unroll
      for (int r = 0; r < 4; ++r) n[r] = nr[r * NBW];

      // ---- phase A: in-GEMV, full K=64, bias in all 4 owned slots
#pragma unroll
      for (int r = 0; r < 4; ++r) acc[r] = tp + cp[r];
      {
        short8 xh0 = ld_frag16(&Xh[arow * XLDW + kq0]);
        short8 xl0 = ld_frag16(&Xl[arow * XLDW + kq0]);
        short8 xh1 = ld_frag16(&Xh[arow * XLDW + kq1]);
        short8 xl1 = ld_frag16(&Xl[arow * XLDW + kq1]);
        acc = __builtin_amdgcn_mfma_f32_16x16x32_bf16(xl0, wiH0, acc, 0, 0, 0);
        acc = __builtin_amdgcn_mfma_f32_16x16x32_bf16(xh0, wiL0, acc, 0, 0, 0);
        acc = __builtin_amdgcn_mfma_f32_16x16x32_bf16(xh0, wiH0, acc, 0, 0, 0);
        acc = __builtin_amdgcn_mfma_f32_16x16x32_bf16(xl1, wiH1, acc, 0, 0, 0);
        acc = __builtin_amdgcn_mfma_f32_16x16x32_bf16(xh1, wiL1, acc, 0, 0, 0);
        acc = __builtin_amdgcn_mfma_f32_16x16x32_bf16(xh1, wiH1, acc, 0, 0, 0);
      }
#pragma unroll
      for (int r = 0; r < 4; ++r) {
        float v = acc[r];
        v = v * __builtin_amdgcn_rcpf(1.0f + __expf(-v));
        short h, l;
        split_bf16(v, h, l);
        Hh[(rowb + r) * XLDW + dim] = h; Hl[(rowb + r) * XLDW + dim] = l;
      }
      int tn = (t > 0) ? (t - 1) : 0;
      tpn = tpb[tn * 64 + dim];                    // prefetch next tp
    } else if (t > 0) {
      // noise for step t-1, first half
      gk0 = su[(t - 1) * 8 + 5];
      gk1 = su[(t - 1) * 8 + 6];
      nd = nb_w + ((t - 1) & 1) * 16 * NBW;
      nd[0] = jax_bits_to_normal(jax_random_bits32(gk0, gk1, jn + 0u));
      nd[1] = jax_bits_to_normal(jax_random_bits32(gk0, gk1, jn + 1u));
    }
    __syncthreads();                                // B1

    if (gemv) {
      // ---- phase B: out-GEMV, full K=64, update 4 cells, restage X
      f32x4 eac;
#pragma unroll
      for (int r = 0; r < 4; ++r) eac[r] = bo;
      {
        short8 hh0 = ld_frag16(&Hh[arow * XLDW + kq0]);
        short8 hl0 = ld_frag16(&Hl[arow * XLDW + kq0]);
        short8 hh1 = ld_frag16(&Hh[arow * XLDW + kq1]);
        short8 hl1 = ld_frag16(&Hl[arow * XLDW + kq1]);
        eac = __builtin_amdgcn_mfma_f32_16x16x32_bf16(hl0, woH0, eac, 0, 0, 0);
        eac = __builtin_amdgcn_mfma_f32_16x16x32_bf16(hh0, woL0, eac, 0, 0, 0);
        eac = __builtin_amdgcn_mfma_f32_16x16x32_bf16(hh0, woH0, eac, 0, 0, 0);
        eac = __builtin_amdgcn_mfma_f32_16x16x32_bf16(hl1, woH1, eac, 0, 0, 0);
        eac = __builtin_amdgcn_mfma_f32_16x16x32_bf16(hh1, woL1, eac, 0, 0, 0);
        eac = __builtin_amdgcn_mfma_f32_16x16x32_bf16(hh1, woH1, eac, 0, 0, 0);
      }
#pragma unroll
      for (int r = 0; r < 4; ++r) {
        float xc = fminf(1.f, fmaxf(-1.f, sr * xo[r] - srm1 * eac[r]));
        xo[r] = c1 * xc + c2 * xo[r] + sg * n[r];
        short h, l;
        split_bf16(xo[r], h, l);
        Xh[(rowb + r) * XLDW + dim] = h; Xl[(rowb + r) * XLDW + dim] = l;
      }
      tp = tpn;
    } else if (t > 0) {
      // noise for step t-1, second half
      nd[2] = jax_bits_to_normal(jax_random_bits32(gk0, gk1, jn + 2u));
      nd[3] = jax_bits_to_normal(jax_random_bits32(gk0, gk1, jn + 3u));
    }
    __syncthreads();                                // B2
  }

  if (gemv) {
#pragma unroll
    for (int r = 0; r < 4; ++r) out[j0 + r * 64u] = xo[r];
  }
}

// ---------------------------------------------------------------------------
extern "C" void kernel_launch(void* const* d_in, const int* in_sizes, int n_in,
                              void* d_out, int out_size, void* d_ws, size_t ws_size,
                              hipStream_t stream)
{
  const int*   seq  = (const int*)  d_in[0];
  const float* emb  = (const float*)d_in[1];
  const float* W1   = (const float*)d_in[2];
  const float* b1   = (const float*)d_in[3];
  const float* W2   = (const float*)d_in[4];
  const float* b2   = (const float*)d_in[5];
  const float* Win  = (const float*)d_in[6];
  const float* bin  = (const float*)d_in[7];
  const float* Wt   = (const float*)d_in[8];
  const float* bt   = (const float*)d_in[9];
  const float* Wc   = (const float*)d_in[10];
  const float* bc   = (const float*)d_in[11];
  const float* Wout = (const float*)d_in[12];
  const float* bout = (const float*)d_in[13];

  float* out   = (float*)d_out;
  float* ws    = (float*)d_ws;
  float* cproj = ws;                       // 524288 floats
  float* tpb   = ws + 524288;              // 12800 floats
  float* sched = ws + 524288 + 12800;      // 1600 floats (t*8 layout)
  float* pooled = out;                     // reuse d_out as scratch

  k_pool <<<2048, 256, 0, stream>>>(seq, emb, pooled);
  k_enc  <<<1024, 256, 0, stream>>>(pooled, W1, b1, W2, b2, Wc, bc, cproj);
  k_prep <<<200, 64, 0, stream>>>(Wt, bt, bin, tpb, sched);
  k_ddpm <<<512, 512, 0, stream>>>(Win, Wout, bout, cproj, tpb, sched, out);
}